// Round 7
// baseline (129.521 us; speedup 1.0000x reference)
//
#include <hip/hip_runtime.h>
#include <hip/hip_bf16.h>
#include <hip/hip_cooperative_groups.h>

namespace cg = cooperative_groups;

// CosSim_Loss: pred [32, 8, 512, 512] f32 -> scalar mean of per-batch 8x8
// cosine-similarity Gram matrices (diag forced to 1).
//
// Round-7: R3/R5/R6 triangulate the read path at ~5.6 TB/s (three different
// staging structures within 1.5%) -> remaining cost is the ~4us finalize
// dispatch + graph edge. Fuse finalize into the partial kernel with a
// cooperative grid sync (single dispatch). 256 blocks x 512 threads x 134KB
// LDS = exactly 1 block/CU -> co-residency for grid.sync() holds.
// Fallback to the proven two-kernel path if cooperative launch errors.
//
// ws layout: float pw[NB][NACC][GX] = 32*36*8*4 = 36864 B.

#define NB 32      // batches
#define NM 8       // maps per batch
#define L4 65536   // (512*512)/4 float4 per row
#define NACC 36    // 8 norms + 28 pairs
#define GX 8       // blocks per batch -> 256 blocks, 1/CU
#define TPB 512    // threads per block (8 waves)
#define CH 512     // float4 per row per chunk (8 KB/row, 64 KB all rows)
#define ITERS 16   // (L4/GX)/CH

// Per-block accumulate: reads this block's L-range of all 8 rows via
// global_load_lds double buffer (lane-linear slots => no barriers; per-wave
// counted vmcnt orders chunk n vs n+1), reduces to 36 partials, writes
// pw[b][k][gx].
__device__ __forceinline__ void cossim_block(
    const float4* __restrict__ x, float* __restrict__ pw) {
    __shared__ float4 buf[2][NM][CH];   // 128 KB
    const int b = blockIdx.y;
    const int tid = threadIdx.x;
    const float4* g = x + (size_t)b * NM * L4 + (size_t)blockIdx.x * (L4 / GX) + tid;

    #pragma unroll
    for (int i = 0; i < NM; ++i) {
        __builtin_amdgcn_global_load_lds(
            (const __attribute__((address_space(1))) void*)(g + (size_t)i * L4),
            (__attribute__((address_space(3))) void*)(&buf[0][i][tid]),
            16, 0, 0);
    }

    float acc[NACC];
    #pragma unroll
    for (int k = 0; k < NACC; ++k) acc[k] = 0.0f;

    for (int it = 0; it < ITERS; ++it) {
        if (it + 1 < ITERS) {
            const float4* gn = g + (size_t)(it + 1) * CH;
            #pragma unroll
            for (int i = 0; i < NM; ++i) {
                __builtin_amdgcn_global_load_lds(
                    (const __attribute__((address_space(1))) void*)(gn + (size_t)i * L4),
                    (__attribute__((address_space(3))) void*)(&buf[(it + 1) & 1][i][tid]),
                    16, 0, 0);
            }
            asm volatile("s_waitcnt vmcnt(8)" ::: "memory");
        } else {
            asm volatile("s_waitcnt vmcnt(0)" ::: "memory");
        }

        float4 v[NM];
        #pragma unroll
        for (int i = 0; i < NM; ++i) v[i] = buf[it & 1][i][tid];

        #pragma unroll
        for (int i = 0; i < NM; ++i) {
            acc[i] += v[i].x * v[i].x + v[i].y * v[i].y
                    + v[i].z * v[i].z + v[i].w * v[i].w;
        }
        int k = NM;
        #pragma unroll
        for (int i = 0; i < NM; ++i) {
            #pragma unroll
            for (int j = i + 1; j < NM; ++j) {
                acc[k] += v[i].x * v[j].x + v[i].y * v[j].y
                        + v[i].z * v[j].z + v[i].w * v[j].w;
                ++k;
            }
        }
    }

    // wave64 shuffle reduction per accumulator
    #pragma unroll
    for (int k = 0; k < NACC; ++k) {
        float s = acc[k];
        #pragma unroll
        for (int off = 32; off > 0; off >>= 1) s += __shfl_down(s, off, 64);
        acc[k] = s;   // valid in lane 0 of each wave
    }

    // block-level reduction in LDS: 8 waves -> 36 values
    __shared__ float red[TPB / 64][NACC];
    const int wave = threadIdx.x >> 6;
    if ((threadIdx.x & 63) == 0) {
        #pragma unroll
        for (int k = 0; k < NACC; ++k) red[wave][k] = acc[k];
    }
    __syncthreads();
    if (threadIdx.x < NACC) {
        float s = 0.0f;
        #pragma unroll
        for (int w = 0; w < TPB / 64; ++w) s += red[w][threadIdx.x];
        pw[((size_t)b * NACC + threadIdx.x) * GX + blockIdx.x] = s;
    }
}

__device__ __forceinline__ float batch_score(const float* w) {
    // w[0..7] = sumsq, w[8..35] = cross dots (i<j)
    float n[NM];
    #pragma unroll
    for (int i = 0; i < NM; ++i) n[i] = fmaxf(sqrtf(w[i]), 1e-8f);
    float s = 0.0f;
    int k = NM;
    #pragma unroll
    for (int i = 0; i < NM; ++i) {
        #pragma unroll
        for (int j = i + 1; j < NM; ++j) {
            s += w[k] / (n[i] * n[j]);
            ++k;
        }
    }
    return 2.0f * s + (float)NM;
}

__global__ __launch_bounds__(TPB, 1) void cossim_fused(
    const float4* __restrict__ x, float* __restrict__ pw,
    float* __restrict__ out) {
    cossim_block(x, pw);
    __threadfence();
    cg::this_grid().sync();

    if (blockIdx.x == 0 && blockIdx.y == 0) {
        __shared__ float fin[NB][NACC];
        for (int p = threadIdx.x; p < NB * NACC; p += TPB) {
            const float4* src = (const float4*)(pw + (size_t)p * GX);
            float4 s0 = src[0], s1 = src[1];
            fin[p / NACC][p % NACC] = (s0.x + s0.y + s0.z + s0.w)
                                    + (s1.x + s1.y + s1.z + s1.w);
        }
        __syncthreads();
        if (threadIdx.x < 64) {
            float bs = (threadIdx.x < NB) ? batch_score(fin[threadIdx.x]) : 0.0f;
            #pragma unroll
            for (int off = 32; off > 0; off >>= 1) bs += __shfl_down(bs, off, 64);
            if (threadIdx.x == 0) out[0] = bs / (float)(NB * NM * NM);
        }
    }
}

// ---- fallback: proven R6 two-kernel path ----

__global__ __launch_bounds__(TPB, 1) void cossim_partial_k(
    const float4* __restrict__ x, float* __restrict__ pw) {
    cossim_block(x, pw);
}

__global__ __launch_bounds__(1024) void cossim_finalize_direct(
    const float* __restrict__ pw, float* __restrict__ out) {
    __shared__ float fin[NB][NACC];
    const int tid = threadIdx.x;

    for (int p = tid; p < NB * NACC; p += 1024) {
        const float4* src = (const float4*)(pw + (size_t)p * GX);
        float4 s0 = src[0], s1 = src[1];
        fin[p / NACC][p % NACC] = (s0.x + s0.y + s0.z + s0.w)
                                + (s1.x + s1.y + s1.z + s1.w);
    }
    __syncthreads();

    if (tid < 64) {
        float bs = (tid < NB) ? batch_score(fin[tid]) : 0.0f;
        #pragma unroll
        for (int off = 32; off > 0; off >>= 1) bs += __shfl_down(bs, off, 64);
        if (tid == 0) out[0] = bs / (float)(NB * NM * NM);
    }
}

extern "C" void kernel_launch(void* const* d_in, const int* in_sizes, int n_in,
                              void* d_out, int out_size, void* d_ws, size_t ws_size,
                              hipStream_t stream) {
    const float4* x = (const float4*)d_in[0];
    float* out = (float*)d_out;
    float* ws = (float*)d_ws;

    dim3 grid(GX, NB);   // 8 chunks per batch x 32 batches = 256 blocks

    void* args[] = {(void*)&x, (void*)&ws, (void*)&out};
    hipError_t err = hipLaunchCooperativeKernel(
        (const void*)cossim_fused, grid, dim3(TPB), args, 0u, stream);

    if (err != hipSuccess) {
        // cooperative launch unsupported here -> proven two-kernel path
        cossim_partial_k<<<grid, TPB, 0, stream>>>(x, ws);
        cossim_finalize_direct<<<1, 1024, 0, stream>>>(ws, out);
    }
}

// Round 8
// 52.981 us; speedup vs baseline: 2.4447x; 2.4447x over previous
//
#include <hip/hip_runtime.h>
#include <hip/hip_bf16.h>

// CosSim_Loss: pred [32, 8, 512, 512] f32 -> scalar mean of per-batch 8x8
// cosine-similarity Gram matrices (diag forced to 1).
//
// Round-8: revert to the proven R6 two-kernel structure (53.4 us).
// R7's cooperative fusion regressed 2.4x: identical FETCH_SIZE but ~800 GB/s
// effective -> ROCm cooperative dispatch throttles the VMEM path; grid-sync
// fusion is strictly worse than the ~3 us finalize dispatch it removes.
//
// Structure: 256 blocks (1/CU) x 512 threads; each block reads its L-range of
// all 8 rows of one batch via global_load_lds double buffer (2x64 KB LDS,
// lane-linear slots => LDS acts as a thread-private prefetch buffer => no
// barriers; per-wave counted s_waitcnt vmcnt(8) orders chunk n vs n+1).
// 36 accumulators/thread (8 sumsq + 28 cross dots), wave shuffle-reduce,
// block LDS-reduce, race-free per-block slots; tiny finalize kernel does the
// sqrt/divide/mean.
//
// ws layout: float pw[NB][NACC][GX] = 32*36*8*4 = 36864 B.

#define NB 32      // batches
#define NM 8       // maps per batch
#define L4 65536   // (512*512)/4 float4 per row
#define NACC 36    // 8 norms + 28 pairs
#define GX 8       // blocks per batch -> 256 blocks, 1/CU
#define TPB 512    // threads per block (8 waves)
#define CH 512     // float4 per row per chunk (8 KB/row, 64 KB all rows)
#define ITERS 16   // (L4/GX)/CH

template <bool DIRECT>
__global__ __launch_bounds__(TPB, 1) void cossim_partial(
    const float4* __restrict__ x, float* __restrict__ ws) {
    __shared__ float4 buf[2][NM][CH];   // 128 KB
    const int b = blockIdx.y;
    const int tid = threadIdx.x;
    const float4* g = x + (size_t)b * NM * L4 + (size_t)blockIdx.x * (L4 / GX) + tid;

    // prologue: stage chunk 0 -> buf[0]
    #pragma unroll
    for (int i = 0; i < NM; ++i) {
        __builtin_amdgcn_global_load_lds(
            (const __attribute__((address_space(1))) void*)(g + (size_t)i * L4),
            (__attribute__((address_space(3))) void*)(&buf[0][i][tid]),
            16, 0, 0);
    }

    float acc[NACC];
    #pragma unroll
    for (int k = 0; k < NACC; ++k) acc[k] = 0.0f;

    for (int it = 0; it < ITERS; ++it) {
        if (it + 1 < ITERS) {
            const float4* gn = g + (size_t)(it + 1) * CH;
            #pragma unroll
            for (int i = 0; i < NM; ++i) {
                __builtin_amdgcn_global_load_lds(
                    (const __attribute__((address_space(1))) void*)(gn + (size_t)i * L4),
                    (__attribute__((address_space(3))) void*)(&buf[(it + 1) & 1][i][tid]),
                    16, 0, 0);
            }
            // our own chunk-it loads (issued last iter) are the oldest 8 of 16
            asm volatile("s_waitcnt vmcnt(8)" ::: "memory");
        } else {
            asm volatile("s_waitcnt vmcnt(0)" ::: "memory");
        }

        float4 v[NM];
        #pragma unroll
        for (int i = 0; i < NM; ++i) v[i] = buf[it & 1][i][tid];

        #pragma unroll
        for (int i = 0; i < NM; ++i) {
            acc[i] += v[i].x * v[i].x + v[i].y * v[i].y
                    + v[i].z * v[i].z + v[i].w * v[i].w;
        }
        int k = NM;
        #pragma unroll
        for (int i = 0; i < NM; ++i) {
            #pragma unroll
            for (int j = i + 1; j < NM; ++j) {
                acc[k] += v[i].x * v[j].x + v[i].y * v[j].y
                        + v[i].z * v[j].z + v[i].w * v[j].w;
                ++k;
            }
        }
    }

    // wave64 shuffle reduction per accumulator
    #pragma unroll
    for (int k = 0; k < NACC; ++k) {
        float s = acc[k];
        #pragma unroll
        for (int off = 32; off > 0; off >>= 1) s += __shfl_down(s, off, 64);
        acc[k] = s;   // valid in lane 0 of each wave
    }

    // block-level reduction in LDS: 8 waves -> 36 values
    __shared__ float red[TPB / 64][NACC];
    const int wave = threadIdx.x >> 6;
    if ((threadIdx.x & 63) == 0) {
        #pragma unroll
        for (int k = 0; k < NACC; ++k) red[wave][k] = acc[k];
    }
    __syncthreads();
    if (threadIdx.x < NACC) {
        float s = 0.0f;
        #pragma unroll
        for (int w = 0; w < TPB / 64; ++w) s += red[w][threadIdx.x];
        if (DIRECT) {
            ws[((size_t)b * NACC + threadIdx.x) * GX + blockIdx.x] = s;
        } else {
            atomicAdd(&ws[b * NACC + threadIdx.x], s);
        }
    }
}

__device__ __forceinline__ float batch_score(const float* w) {
    // w[0..7] = sumsq, w[8..35] = cross dots (i<j)
    float n[NM];
    #pragma unroll
    for (int i = 0; i < NM; ++i) n[i] = fmaxf(sqrtf(w[i]), 1e-8f);
    float s = 0.0f;
    int k = NM;
    #pragma unroll
    for (int i = 0; i < NM; ++i) {
        #pragma unroll
        for (int j = i + 1; j < NM; ++j) {
            s += w[k] / (n[i] * n[j]);
            ++k;
        }
    }
    return 2.0f * s + (float)NM;
}

__global__ __launch_bounds__(1024) void cossim_finalize_direct(
    const float* __restrict__ pw, float* __restrict__ out) {
    __shared__ float fin[NB][NACC];
    const int tid = threadIdx.x;

    for (int p = tid; p < NB * NACC; p += 1024) {
        const float4* src = (const float4*)(pw + (size_t)p * GX);
        float4 s0 = src[0], s1 = src[1];
        fin[p / NACC][p % NACC] = (s0.x + s0.y + s0.z + s0.w)
                                + (s1.x + s1.y + s1.z + s1.w);
    }
    __syncthreads();

    if (tid < 64) {
        float bs = (tid < NB) ? batch_score(fin[tid]) : 0.0f;
        #pragma unroll
        for (int off = 32; off > 0; off >>= 1) bs += __shfl_down(bs, off, 64);
        if (tid == 0) out[0] = bs / (float)(NB * NM * NM);
    }
}

__global__ __launch_bounds__(64) void cossim_finalize_atomic(
    const float* __restrict__ ws, float* __restrict__ out) {
    const int b = threadIdx.x;
    float bs = (b < NB) ? batch_score(ws + b * NACC) : 0.0f;
    #pragma unroll
    for (int off = 32; off > 0; off >>= 1) bs += __shfl_down(bs, off, 64);
    if (threadIdx.x == 0) out[0] = bs / (float)(NB * NM * NM);
}

extern "C" void kernel_launch(void* const* d_in, const int* in_sizes, int n_in,
                              void* d_out, int out_size, void* d_ws, size_t ws_size,
                              hipStream_t stream) {
    const float4* x = (const float4*)d_in[0];
    float* out = (float*)d_out;
    float* ws = (float*)d_ws;

    dim3 grid(GX, NB);   // 8 chunks per batch x 32 batches = 256 blocks

    if (ws_size >= (size_t)NB * NACC * GX * sizeof(float)) {
        cossim_partial<true><<<grid, TPB, 0, stream>>>(x, ws);
        cossim_finalize_direct<<<1, 1024, 0, stream>>>(ws, out);
    } else {
        hipMemsetAsync(ws, 0, NB * NACC * sizeof(float), stream);
        cossim_partial<false><<<grid, TPB, 0, stream>>>(x, ws);
        cossim_finalize_atomic<<<1, 64, 0, stream>>>(ws, out);
    }
}